// Round 4
// baseline (145.949 us; speedup 1.0000x reference)
//
#include <hip/hip_runtime.h>
#include <hip/hip_bf16.h>

// B=2,S=2048 -> T=4096 tokens; D=1024; N=64 experts; R=64; TOP_K=2.
// Inputs runtime-detected f32 vs bf16 (measured: f32). Outputs f32 flat:
// [0,262144) proj; [262144,270336) idx; [270336,278528) w.
// R13: R12 never ran (container failed 2x; its 139KB LDS / 1-blk-CU design
// was the riskiest element). Same two theories, safer geometry:
//  - score: unchanged R10 config (8tok x 512blk, measured 43us).
//  - egemm: K-SPLIT persistent-B. 128 blocks = 64 experts x 2 K-halves.
//    Each block stages its 512-K half of B once (4 slabs, 68KB; total LDS
//    87KB) and loops ALL row-tiles of its expert (any cnt<=1024), staging
//    A bulk per tile (8x float4/thread, 3 barriers/tile). B panel read
//    exactly once chip-wide: 134MB -> 16MB; egemm HBM ~48MB (~10us floor).
//    Out gets 4 atomics/element (2 experts x 2 K-halves): order noise
//    ~1e-6, invisible vs 0.0156 bf16 floor.
// Harness d_ws poison fill (~44us) untouchable.
// d_ws: f32 w[t*2] (32KB); int cnt[64]; int list[64*1024] (256KB).

typedef unsigned short u16;
typedef unsigned int u32;
typedef __attribute__((ext_vector_type(8))) short short8;
typedef __attribute__((ext_vector_type(4))) float f32x4;

__device__ __forceinline__ float bf2f(u16 u) {
    u32 v = ((u32)u) << 16; float f; __builtin_memcpy(&f, &v, 4); return f;
}
__device__ __forceinline__ u16 f2bf(float f) {  // RNE
    u32 u; __builtin_memcpy(&u, &f, 4);
    u32 r = u + 0x7fff + ((u >> 16) & 1);
    return (u16)(r >> 16);
}
__device__ __forceinline__ u32 pack2(float a, float b) {
    return ((u32)f2bf(b) << 16) | (u32)f2bf(a);
}

#define T_TOKENS 4096
#define DDIM 1024
#define NEXP 64
#define RDIM 64
#define LCAP 1024
#define OUT_IDX_OFF 262144
#define OUT_W_OFF 270336

struct LdBF {
    const u16* p;
    __device__ __forceinline__ float4 ld4(size_t i) const {
        ushort4 v = *(const ushort4*)(p + i);
        return make_float4(bf2f(v.x), bf2f(v.y), bf2f(v.z), bf2f(v.w));
    }
    __device__ __forceinline__ float ld1(size_t i) const { return bf2f(p[i]); }
};
struct LdF32 {
    const float* p;
    __device__ __forceinline__ float4 ld4(size_t i) const { return *(const float4*)(p + i); }
    __device__ __forceinline__ float ld1(size_t i) const { return p[i]; }
};

// in-block dtype probe: 1 if f32, 0 if bf16 (all blocks same verdict).
__device__ __forceinline__ int detect_f32(const u16* x, int* lds_cnt) {
    if (threadIdx.x == 0) *lds_cnt = 0;
    __syncthreads();
    if (threadIdx.x < 256) {
        unsigned e = (x[threadIdx.x] >> 7) & 0xFF;
        if (e >= 0x68 && e <= 0x88) atomicAdd(lds_cnt, 1);
    }
    __syncthreads();
    int f = (*lds_cnt < 200) ? 1 : 0;
    __syncthreads();
    return f;
}

// ---------------- Kernel A: score GEMM + top2 + softmax + expert lists ----
// 512 blocks x 256 thr; 8 tokens/block; K-chunks of 64, order rotated by
// blockIdx&15 (deterministic per block; de-lockstep HBM/L2 bursts).
// Lane: tg=lane&1 (tokens tg+2mi, mi<4), eg=(lane>>1)&7 (experts eg+8ei,
// ei<8), kql=(lane>>4)&3; k-quad per chunk dd = 4*kql + 16*wv.
// Cross-wave k-reduce: shfl_xor(16,32) then sequential wave phases (determ.).
template <class LD>
__device__ __forceinline__ void score_body(LD xld, LD rwld,
                                           float* xs /*8*68*/, float* wt /*64*68*/,
                                           float* sc /*8*65*/,
                                           float* out, float* wsW,
                                           int* wsCnt, int* wsList) {
    const int tid = threadIdx.x;
    const size_t t0 = (size_t)blockIdx.x * 8;
    const int wv = tid >> 6;
    const int lane = tid & 63;
    const int tg = lane & 1;
    const int eg = (lane >> 1) & 7;
    const int kql = (lane >> 4) & 3;
    const int dd = 4 * kql + 16 * wv;
    const int kc0 = blockIdx.x & 15;   // rotated K start

    // zero this block's 8x64 proj out-region (egemm atomically accumulates)
    if (tid < 128) {
        float4 z = make_float4(0.f, 0.f, 0.f, 0.f);
        ((float4*)out)[(size_t)blockIdx.x * 128 + tid] = z;
    }

    const int sm = tid >> 4;            // staging roles (coalesced)
    const int sd4 = (tid & 15) * 4;

    float acc[4][8];
#pragma unroll
    for (int mi = 0; mi < 4; ++mi)
#pragma unroll
        for (int ei = 0; ei < 8; ++ei) acc[mi][ei] = 0.f;

    float4 px;
    if (tid < 128) px = xld.ld4((t0 + sm) * DDIM + kc0 * 64 + sd4);
    float4 pw[4];
#pragma unroll
    for (int h = 0; h < 4; ++h) {
        int i4 = tid + h * 256;
        pw[h] = rwld.ld4((size_t)(i4 >> 4) * DDIM + kc0 * 64 + (i4 & 15) * 4);
    }

    for (int i = 0; i < 16; ++i) {
        if (i > 0) __syncthreads();
        if (tid < 128) *(float4*)&xs[sm * 68 + sd4] = px;
#pragma unroll
        for (int h = 0; h < 4; ++h) {
            int i4 = tid + h * 256;
            *(float4*)&wt[(i4 >> 4) * 68 + (i4 & 15) * 4] = pw[h];
        }
        __syncthreads();

        if (i < 15) {
            int kn = ((i + 1 + kc0) & 15) * 64;
            if (tid < 128) px = xld.ld4((t0 + sm) * DDIM + kn + sd4);
#pragma unroll
            for (int h = 0; h < 4; ++h) {
                int i4 = tid + h * 256;
                pw[h] = rwld.ld4((size_t)(i4 >> 4) * DDIM + kn + (i4 & 15) * 4);
            }
        }

        float4 xv[4], wv4[8];
#pragma unroll
        for (int mi = 0; mi < 4; ++mi)
            xv[mi] = *(const float4*)&xs[(tg + 2 * mi) * 68 + dd];
#pragma unroll
        for (int ei = 0; ei < 8; ++ei)
            wv4[ei] = *(const float4*)&wt[(eg + 8 * ei) * 68 + dd];
#pragma unroll
        for (int mi = 0; mi < 4; ++mi)
#pragma unroll
            for (int ei = 0; ei < 8; ++ei)
                acc[mi][ei] += xv[mi].x * wv4[ei].x + xv[mi].y * wv4[ei].y +
                               xv[mi].z * wv4[ei].z + xv[mi].w * wv4[ei].w;
    }

    // in-wave k-quad reduce (deterministic tree over kql)
#pragma unroll
    for (int mi = 0; mi < 4; ++mi)
#pragma unroll
        for (int ei = 0; ei < 8; ++ei) {
            float v = acc[mi][ei];
            v += __shfl_xor(v, 16, 64);
            v += __shfl_xor(v, 32, 64);
            acc[mi][ei] = v;
        }
    __syncthreads();

    // cross-wave reduce: sequential wave phases (deterministic order)
    for (int w = 0; w < 4; ++w) {
        if (wv == w && kql == 0) {
#pragma unroll
            for (int mi = 0; mi < 4; ++mi)
#pragma unroll
                for (int ei = 0; ei < 8; ++ei) {
                    int idx = (tg + 2 * mi) * 65 + eg + 8 * ei;
                    sc[idx] = (w == 0) ? acc[mi][ei] : sc[idx] + acc[mi][ei];
                }
        }
        __syncthreads();
    }

    if (tid < 8) {
        const float* s = &sc[tid * 65];
        float best = -1e30f, secv = -1e30f;
        int bi = 0, si = 0;
        for (int j = 0; j < NEXP; ++j) {
            float v = s[j];
            if (v > best) { secv = best; si = bi; best = v; bi = j; }
            else if (v > secv) { secv = v; si = j; }
        }
        float w0 = 1.0f / (1.0f + expf(secv - best));
        float w1 = 1.0f - w0;
        size_t t = t0 + tid;
        out[OUT_IDX_OFF + t * 2 + 0] = (float)bi;
        out[OUT_IDX_OFF + t * 2 + 1] = (float)si;
        out[OUT_W_OFF + t * 2 + 0] = w0;
        out[OUT_W_OFF + t * 2 + 1] = w1;
        wsW[t * 2 + 0] = w0;
        wsW[t * 2 + 1] = w1;
        int p0 = atomicAdd(&wsCnt[bi], 1);
        if (p0 < LCAP) wsList[bi * LCAP + p0] = (int)(t * 2 + 0);
        int p1 = atomicAdd(&wsCnt[si], 1);
        if (p1 < LCAP) wsList[si * LCAP + p1] = (int)(t * 2 + 1);
    }
}

__global__ __launch_bounds__(256, 2) void score_topk(const void* x, const void* rw,
                                                     float* out, float* wsW,
                                                     int* wsCnt, int* wsList) {
    __shared__ float xs[8 * 68];
    __shared__ float wt[64 * 68];
    __shared__ float sc[8 * 65];
    __shared__ int dc;
    int f = detect_f32((const u16*)x, &dc);
    if (f)
        score_body(LdF32{(const float*)x}, LdF32{(const float*)rw}, xs, wt, sc, out, wsW, wsCnt, wsList);
    else
        score_body(LdBF{(const u16*)x}, LdBF{(const u16*)rw}, xs, wt, sc, out, wsW, wsCnt, wsList);
}

// ---------------- Kernel B: per-expert bf16 MFMA GEMM, K-split persist-B --
// 128 blocks: e = bid>>1, kh = bid&1 (k in [kh*512, kh*512+512)).
// Stage this K-half of B ONCE: 4 slabs of [64r][68 u32] (68KB LDS; same
// slab layout + MFMA indexing as the proven per-tile kernel). Then loop
// ALL row-tiles of expert e (any cnt<=1024): bulk-stage A (16 x 512 half,
// 8x float4/thread), one MFMA sweep (16 mfma), partial-sum atomicAdd.
// Each B byte read exactly once chip-wide (halves disjoint).
template <class LD>
__device__ __forceinline__ void egemm_body(LD xld, LD nld,
                                           const int* wsCnt, const int* wsList,
                                           const float* wsW, float* out,
                                           u16* Ab /*4*16*136*/, u16* Bb /*4*64*136*/,
                                           int* entL /*16*/) {
    const int tid = threadIdx.x;
    const int e = blockIdx.x >> 1;
    const int kh = blockIdx.x & 1;
    const int cntE = min(wsCnt[e], LCAP);
    if (cntE <= 0) return;                       // uniform exit
    const int wv = tid >> 6;
    const int lane = tid & 63;
    const int l15 = lane & 15, quad = lane >> 4;
    const size_t nbase = (size_t)e * (DDIM * RDIM);

    // ---- stage K-half of B once: slab s covers k in [kh*512+128s, +128)
    // tasks per slab: rq=tid&15 (col group rq*4..+3), kp=(tid>>4)+16h
    const int rq = tid & 15;
    const int kpB = tid >> 4;
    for (int s = 0; s < 4; ++s) {
        u32* bb = (u32*)Bb + s * (64 * 68);
        const int k0c = kh * 512 + s * 128;
#pragma unroll
        for (int h = 0; h < 4; ++h) {
            int kp = kpB + h * 16;
            float4 g0 = nld.ld4(nbase + (size_t)(k0c + 2 * kp) * RDIM + rq * 4);
            float4 g1 = nld.ld4(nbase + (size_t)(k0c + 2 * kp + 1) * RDIM + rq * 4);
            bb[(rq * 4 + 0) * 68 + kp] = pack2(g0.x, g1.x);
            bb[(rq * 4 + 1) * 68 + kp] = pack2(g0.y, g1.y);
            bb[(rq * 4 + 2) * 68 + kp] = pack2(g0.z, g1.z);
            bb[(rq * 4 + 3) * 68 + kp] = pack2(g0.w, g1.w);
        }
    }
    // Bb visibility: first tile's first __syncthreads below.

    const int rowA = tid >> 4;
    const int kqA = tid & 15;

    for (int ti = 0; ti * 16 < cntE; ++ti) {
        const int base = ti * 16;
        const int valid = min(16, cntE - base);
        __syncthreads();   // prev tile MFMA reads of Ab/entL done; Bb visible
        if (tid < 16)
            entL[tid] = wsList[e * LCAP + base + min(tid, valid - 1)];
        __syncthreads();
        const size_t xrow = (size_t)(entL[rowA] >> 1) * DDIM + kh * 512;

        // bulk A stage: 8 float4 loads issued back-to-back, then pack+write
        float4 a0[4], a1[4];
#pragma unroll
        for (int kc = 0; kc < 4; ++kc) {
            a0[kc] = xld.ld4(xrow + kc * 128 + kqA * 8);
            a1[kc] = xld.ld4(xrow + kc * 128 + kqA * 8 + 4);
        }
#pragma unroll
        for (int kc = 0; kc < 4; ++kc) {
            uint4 w;
            w.x = pack2(a0[kc].x, a0[kc].y);
            w.y = pack2(a0[kc].z, a0[kc].w);
            w.z = pack2(a1[kc].x, a1[kc].y);
            w.w = pack2(a1[kc].z, a1[kc].w);
            *(uint4*)&((u32*)Ab)[kc * (16 * 68) + rowA * 68 + kqA * 4] = w;
        }
        __syncthreads();

        f32x4 acc = {0.f, 0.f, 0.f, 0.f};
#pragma unroll
        for (int kc = 0; kc < 4; ++kc)
#pragma unroll
            for (int ko = 0; ko < 4; ++ko) {
                int kofs = ko * 32 + quad * 8;
                short8 bfr = *(const short8*)&Bb[kc * (64 * 136) + (16 * wv + l15) * 136 + kofs];
                short8 af = *(const short8*)&Ab[kc * (16 * 136) + l15 * 136 + kofs];
                acc = __builtin_amdgcn_mfma_f32_16x16x32_bf16(af, bfr, acc, 0, 0, 0);
            }

        // D: row (token m) = quad*4+reg, col r = 16*wv + l15
#pragma unroll
        for (int reg = 0; reg < 4; ++reg) {
            int m = quad * 4 + reg;
            if (m < valid) {
                int t2 = entL[m];
                atomicAdd(&out[(size_t)(t2 >> 1) * RDIM + 16 * wv + l15], wsW[t2] * acc[reg]);
            }
        }
    }
}

__global__ __launch_bounds__(256, 1) void expert_gemm(const void* x, const void* neurons,
                                                      const int* wsCnt, const int* wsList,
                                                      const float* wsW, float* out) {
    __shared__ u16 Ab[4 * 16 * 136];
    __shared__ u16 Bb[4 * 64 * 136];
    __shared__ int entL[16];
    __shared__ int dc;
    int f = detect_f32((const u16*)x, &dc);
    if (f)
        egemm_body(LdF32{(const float*)x}, LdF32{(const float*)neurons}, wsCnt, wsList, wsW, out, Ab, Bb, entL);
    else
        egemm_body(LdBF{(const u16*)x}, LdBF{(const u16*)neurons}, wsCnt, wsList, wsW, out, Ab, Bb, entL);
}

extern "C" void kernel_launch(void* const* d_in, const int* in_sizes, int n_in,
                              void* d_out, int out_size, void* d_ws, size_t ws_size,
                              hipStream_t stream) {
    const void* x = d_in[0];
    const void* rw = d_in[1];
    const void* neurons = d_in[2];
    float* out = (float*)d_out;

    char* wsc = (char*)d_ws;
    float* wsW = (float*)wsc;                                  // 32 KB
    int* wsCnt = (int*)(wsc + 32 * 1024);                      // 256 B
    int* wsList = (int*)((char*)wsCnt + 256);                  // 256 KB

    hipMemsetAsync(wsCnt, 0, 256, stream);
    score_topk<<<512, 256, 0, stream>>>(x, rw, out, wsW, wsCnt, wsList);
    expert_gemm<<<128, 256, 0, stream>>>(x, neurons, wsCnt, wsList, wsW, out);
}

// Round 5
// 126.114 us; speedup vs baseline: 1.1573x; 1.1573x over previous
//
#include <hip/hip_runtime.h>
#include <hip/hip_bf16.h>

// B=2,S=2048 -> T=4096 tokens; D=1024; N=64 experts; R=64; TOP_K=2.
// Inputs runtime-detected f32 vs bf16 (measured: f32). Outputs f32 flat:
// [0,262144) proj; [262144,270336) idx; [270336,278528) w.
// R14: R13 post-mortem: K-split persistent-B got the traffic win but LOST
// 17us to serialization (128 blocks = half chip idle; per-tile serial chain
// entL-load -> A-gather -> MFMA -> syncthreads draining 1M contended
// cross-XCD atomicAdds). This round keeps B-read-once (16MB) and removes
// every serialization source:
//  - atomics -> plain stores of partials P[t2][oct][r] (each cell written
//    once; deterministic) + 1024-block combine kernel (sums 16 partials).
//  - K-eighths: 512 blocks (e=bid>>3, oct=bid&7), 26KB LDS -> 2 blocks/CU.
//  - expert token list preloaded to LDS once (kills per-tile entL stall);
//    register prefetch overlaps tile t+1 A-loads with tile t MFMA+stores.
//  - score: identical to the measured-43us R10 config, minus proj zeroing
//    (combine overwrites all of proj).
// Harness d_ws poison fill (~44us) untouchable.
// d_ws: f32 w[8192] (32KB); int cnt[64]; int list[64*1024] (256KB);
//       P f32[8192][8][64] @ +1MB (16MB). ws >= 256MB (poison fill writes 268MB).

typedef unsigned short u16;
typedef unsigned int u32;
typedef __attribute__((ext_vector_type(8))) short short8;
typedef __attribute__((ext_vector_type(4))) float f32x4;

__device__ __forceinline__ float bf2f(u16 u) {
    u32 v = ((u32)u) << 16; float f; __builtin_memcpy(&f, &v, 4); return f;
}
__device__ __forceinline__ u16 f2bf(float f) {  // RNE
    u32 u; __builtin_memcpy(&u, &f, 4);
    u32 r = u + 0x7fff + ((u >> 16) & 1);
    return (u16)(r >> 16);
}
__device__ __forceinline__ u32 pack2(float a, float b) {
    return ((u32)f2bf(b) << 16) | (u32)f2bf(a);
}

#define T_TOKENS 4096
#define DDIM 1024
#define NEXP 64
#define RDIM 64
#define LCAP 1024
#define OUT_IDX_OFF 262144
#define OUT_W_OFF 270336

struct LdBF {
    const u16* p;
    __device__ __forceinline__ float4 ld4(size_t i) const {
        ushort4 v = *(const ushort4*)(p + i);
        return make_float4(bf2f(v.x), bf2f(v.y), bf2f(v.z), bf2f(v.w));
    }
    __device__ __forceinline__ float ld1(size_t i) const { return bf2f(p[i]); }
};
struct LdF32 {
    const float* p;
    __device__ __forceinline__ float4 ld4(size_t i) const { return *(const float4*)(p + i); }
    __device__ __forceinline__ float ld1(size_t i) const { return p[i]; }
};

// in-block dtype probe: 1 if f32, 0 if bf16 (all blocks same verdict).
__device__ __forceinline__ int detect_f32(const u16* x, int* lds_cnt) {
    if (threadIdx.x == 0) *lds_cnt = 0;
    __syncthreads();
    if (threadIdx.x < 256) {
        unsigned e = (x[threadIdx.x] >> 7) & 0xFF;
        if (e >= 0x68 && e <= 0x88) atomicAdd(lds_cnt, 1);
    }
    __syncthreads();
    int f = (*lds_cnt < 200) ? 1 : 0;
    __syncthreads();
    return f;
}

// ---------------- Kernel A: score GEMM + top2 + softmax + expert lists ----
// 512 blocks x 256 thr; 8 tokens/block; K-chunks of 64, order rotated by
// blockIdx&15 (de-lockstep HBM/L2 bursts). Measured 43.2-44.1us.
// Lane: tg=lane&1 (tokens tg+2mi, mi<4), eg=(lane>>1)&7 (experts eg+8ei,
// ei<8), kql=(lane>>4)&3; k-quad per chunk dd = 4*kql + 16*wv.
template <class LD>
__device__ __forceinline__ void score_body(LD xld, LD rwld,
                                           float* xs /*8*68*/, float* wt /*64*68*/,
                                           float* sc /*8*65*/,
                                           float* out, float* wsW,
                                           int* wsCnt, int* wsList) {
    const int tid = threadIdx.x;
    const size_t t0 = (size_t)blockIdx.x * 8;
    const int wv = tid >> 6;
    const int lane = tid & 63;
    const int tg = lane & 1;
    const int eg = (lane >> 1) & 7;
    const int kql = (lane >> 4) & 3;
    const int dd = 4 * kql + 16 * wv;
    const int kc0 = blockIdx.x & 15;   // rotated K start

    const int sm = tid >> 4;            // staging roles (coalesced)
    const int sd4 = (tid & 15) * 4;

    float acc[4][8];
#pragma unroll
    for (int mi = 0; mi < 4; ++mi)
#pragma unroll
        for (int ei = 0; ei < 8; ++ei) acc[mi][ei] = 0.f;

    float4 px;
    if (tid < 128) px = xld.ld4((t0 + sm) * DDIM + kc0 * 64 + sd4);
    float4 pw[4];
#pragma unroll
    for (int h = 0; h < 4; ++h) {
        int i4 = tid + h * 256;
        pw[h] = rwld.ld4((size_t)(i4 >> 4) * DDIM + kc0 * 64 + (i4 & 15) * 4);
    }

    for (int i = 0; i < 16; ++i) {
        if (i > 0) __syncthreads();
        if (tid < 128) *(float4*)&xs[sm * 68 + sd4] = px;
#pragma unroll
        for (int h = 0; h < 4; ++h) {
            int i4 = tid + h * 256;
            *(float4*)&wt[(i4 >> 4) * 68 + (i4 & 15) * 4] = pw[h];
        }
        __syncthreads();

        if (i < 15) {
            int kn = ((i + 1 + kc0) & 15) * 64;
            if (tid < 128) px = xld.ld4((t0 + sm) * DDIM + kn + sd4);
#pragma unroll
            for (int h = 0; h < 4; ++h) {
                int i4 = tid + h * 256;
                pw[h] = rwld.ld4((size_t)(i4 >> 4) * DDIM + kn + (i4 & 15) * 4);
            }
        }

        float4 xv[4], wv4[8];
#pragma unroll
        for (int mi = 0; mi < 4; ++mi)
            xv[mi] = *(const float4*)&xs[(tg + 2 * mi) * 68 + dd];
#pragma unroll
        for (int ei = 0; ei < 8; ++ei)
            wv4[ei] = *(const float4*)&wt[(eg + 8 * ei) * 68 + dd];
#pragma unroll
        for (int mi = 0; mi < 4; ++mi)
#pragma unroll
            for (int ei = 0; ei < 8; ++ei)
                acc[mi][ei] += xv[mi].x * wv4[ei].x + xv[mi].y * wv4[ei].y +
                               xv[mi].z * wv4[ei].z + xv[mi].w * wv4[ei].w;
    }

    // in-wave k-quad reduce (deterministic tree over kql)
#pragma unroll
    for (int mi = 0; mi < 4; ++mi)
#pragma unroll
        for (int ei = 0; ei < 8; ++ei) {
            float v = acc[mi][ei];
            v += __shfl_xor(v, 16, 64);
            v += __shfl_xor(v, 32, 64);
            acc[mi][ei] = v;
        }
    __syncthreads();

    // cross-wave reduce: sequential wave phases (deterministic order)
    for (int w = 0; w < 4; ++w) {
        if (wv == w && kql == 0) {
#pragma unroll
            for (int mi = 0; mi < 4; ++mi)
#pragma unroll
                for (int ei = 0; ei < 8; ++ei) {
                    int idx = (tg + 2 * mi) * 65 + eg + 8 * ei;
                    sc[idx] = (w == 0) ? acc[mi][ei] : sc[idx] + acc[mi][ei];
                }
        }
        __syncthreads();
    }

    if (tid < 8) {
        const float* s = &sc[tid * 65];
        float best = -1e30f, secv = -1e30f;
        int bi = 0, si = 0;
        for (int j = 0; j < NEXP; ++j) {
            float v = s[j];
            if (v > best) { secv = best; si = bi; best = v; bi = j; }
            else if (v > secv) { secv = v; si = j; }
        }
        float w0 = 1.0f / (1.0f + expf(secv - best));
        float w1 = 1.0f - w0;
        size_t t = t0 + tid;
        out[OUT_IDX_OFF + t * 2 + 0] = (float)bi;
        out[OUT_IDX_OFF + t * 2 + 1] = (float)si;
        out[OUT_W_OFF + t * 2 + 0] = w0;
        out[OUT_W_OFF + t * 2 + 1] = w1;
        wsW[t * 2 + 0] = w0;
        wsW[t * 2 + 1] = w1;
        int p0 = atomicAdd(&wsCnt[bi], 1);
        if (p0 < LCAP) wsList[bi * LCAP + p0] = (int)(t * 2 + 0);
        int p1 = atomicAdd(&wsCnt[si], 1);
        if (p1 < LCAP) wsList[si * LCAP + p1] = (int)(t * 2 + 1);
    }
}

__global__ __launch_bounds__(256, 2) void score_topk(const void* x, const void* rw,
                                                     float* out, float* wsW,
                                                     int* wsCnt, int* wsList) {
    __shared__ float xs[8 * 68];
    __shared__ float wt[64 * 68];
    __shared__ float sc[8 * 65];
    __shared__ int dc;
    int f = detect_f32((const u16*)x, &dc);
    if (f)
        score_body(LdF32{(const float*)x}, LdF32{(const float*)rw}, xs, wt, sc, out, wsW, wsCnt, wsList);
    else
        score_body(LdBF{(const u16*)x}, LdBF{(const u16*)rw}, xs, wt, sc, out, wsW, wsCnt, wsList);
}

// ---------------- Kernel B: per-expert bf16 MFMA GEMM, K-eighth persist-B --
// 512 blocks: e = bid>>3, oct = bid&7; k window [oct*128, oct*128+128).
// Stage B eighth ONCE (1 slab [64r][68 u32], 17KB; proven layout/indexing);
// preload expert token list to LDS (<=4KB). Tile loop over 16-row tiles:
// A stage 16x128 (2 float4/thread, register-prefetched one tile ahead),
// 4 MFMA, plain stores of raw partials to P[t2*512 + oct*64 + col].
// No atomics; every P cell written exactly once. LDS ~26KB -> 2 blocks/CU.
template <class LD>
__device__ __forceinline__ void egemm_body(LD xld, LD nld,
                                           const int* wsCnt, const int* wsList,
                                           float* P,
                                           u16* Ab /*16*136*/, u16* Bb /*64*136*/,
                                           int* eL /*1024*/) {
    const int tid = threadIdx.x;
    const int e = blockIdx.x >> 3;
    const int oct = blockIdx.x & 7;
    const int cntE = min(wsCnt[e], LCAP);
    if (cntE <= 0) return;                       // uniform exit
    const int wv = tid >> 6;
    const int lane = tid & 63;
    const int l15 = lane & 15, quad = lane >> 4;
    const size_t nbase = (size_t)e * (DDIM * RDIM);
    const int k0 = oct * 128;

    // preload this expert's token list (read-only afterwards)
    for (int j = tid; j < cntE; j += 256) eL[j] = wsList[e * LCAP + j];

    // stage B eighth once: 128k x 64r; rq=tid&15 (col group), kp=(tid>>4)+16h
    {
        const int rq = tid & 15;
        const int kpB = tid >> 4;
        u32* bb = (u32*)Bb;
#pragma unroll
        for (int h = 0; h < 4; ++h) {
            int kp = kpB + h * 16;
            float4 g0 = nld.ld4(nbase + (size_t)(k0 + 2 * kp) * RDIM + rq * 4);
            float4 g1 = nld.ld4(nbase + (size_t)(k0 + 2 * kp + 1) * RDIM + rq * 4);
            bb[(rq * 4 + 0) * 68 + kp] = pack2(g0.x, g1.x);
            bb[(rq * 4 + 1) * 68 + kp] = pack2(g0.y, g1.y);
            bb[(rq * 4 + 2) * 68 + kp] = pack2(g0.z, g1.z);
            bb[(rq * 4 + 3) * 68 + kp] = pack2(g0.w, g1.w);
        }
    }
    __syncthreads();                              // Bb + eL visible

    const int rowA = tid >> 4;
    const int kqA = tid & 15;
    const int ntiles = (cntE + 15) >> 4;

    // prologue: tile 0 A-loads
    float4 a0, a1;
    {
        int t2r = eL[min(rowA, cntE - 1)];
        size_t xrow = (size_t)(t2r >> 1) * DDIM + k0;
        a0 = xld.ld4(xrow + kqA * 8);
        a1 = xld.ld4(xrow + kqA * 8 + 4);
    }

    for (int ti = 0; ti < ntiles; ++ti) {
        const int base = ti * 16;
        const int valid = min(16, cntE - base);
        if (ti > 0) __syncthreads();             // prev MFMA reads of Ab done
        {
            uint4 w;
            w.x = pack2(a0.x, a0.y);
            w.y = pack2(a0.z, a0.w);
            w.z = pack2(a1.x, a1.y);
            w.w = pack2(a1.z, a1.w);
            *(uint4*)&((u32*)Ab)[rowA * 68 + kqA * 4] = w;
        }
        __syncthreads();                         // Ab ready
        if (ti + 1 < ntiles) {                   // prefetch next tile's A
            int t2r = eL[min(base + 16 + rowA, cntE - 1)];
            size_t xrow = (size_t)(t2r >> 1) * DDIM + k0;
            a0 = xld.ld4(xrow + kqA * 8);
            a1 = xld.ld4(xrow + kqA * 8 + 4);
        }

        f32x4 acc = {0.f, 0.f, 0.f, 0.f};
#pragma unroll
        for (int ko = 0; ko < 4; ++ko) {
            int kofs = ko * 32 + quad * 8;
            short8 bfr = *(const short8*)&Bb[(16 * wv + l15) * 136 + kofs];
            short8 af = *(const short8*)&Ab[l15 * 136 + kofs];
            acc = __builtin_amdgcn_mfma_f32_16x16x32_bf16(af, bfr, acc, 0, 0, 0);
        }

        // D: row (token m) = quad*4+reg, col r = 16*wv + l15 -> raw partial
#pragma unroll
        for (int reg = 0; reg < 4; ++reg) {
            int m = quad * 4 + reg;
            if (m < valid) {
                int t2 = eL[base + m];
                P[(size_t)t2 * 512 + oct * 64 + 16 * wv + l15] = acc[reg];
            }
        }
    }
}

__global__ __launch_bounds__(256, 2) void expert_gemm(const void* x, const void* neurons,
                                                      const int* wsCnt, const int* wsList,
                                                      float* P) {
    __shared__ u16 Ab[16 * 136];
    __shared__ u16 Bb[64 * 136];
    __shared__ int eL[LCAP];
    __shared__ int dc;
    int f = detect_f32((const u16*)x, &dc);
    if (f)
        egemm_body(LdF32{(const float*)x}, LdF32{(const float*)neurons}, wsCnt, wsList, P, Ab, Bb, eL);
    else
        egemm_body(LdBF{(const u16*)x}, LdBF{(const u16*)neurons}, wsCnt, wsList, P, Ab, Bb, eL);
}

// ---------------- Kernel C: combine partials -------------------------------
// out[t][r] = sum_s wsW[2t+s] * sum_oct P[(2t+s)*512 + oct*64 + r].
// 1024 blocks x 256 thr; 1 element/thread; fully coalesced 256B segments.
__global__ __launch_bounds__(256) void combine(const float* P, const float* wsW,
                                               float* out) {
    int i = blockIdx.x * 256 + threadIdx.x;      // [0, 262144)
    int t = i >> 6, r = i & 63;
    const float* p0 = P + (size_t)(2 * t) * 512 + r;
    const float* p1 = P + (size_t)(2 * t + 1) * 512 + r;
    float s0 = 0.f, s1 = 0.f;
#pragma unroll
    for (int o = 0; o < 8; ++o) {
        s0 += p0[o * 64];
        s1 += p1[o * 64];
    }
    out[i] = wsW[2 * t] * s0 + wsW[2 * t + 1] * s1;
}

extern "C" void kernel_launch(void* const* d_in, const int* in_sizes, int n_in,
                              void* d_out, int out_size, void* d_ws, size_t ws_size,
                              hipStream_t stream) {
    const void* x = d_in[0];
    const void* rw = d_in[1];
    const void* neurons = d_in[2];
    float* out = (float*)d_out;

    char* wsc = (char*)d_ws;
    float* wsW = (float*)wsc;                                  // 32 KB
    int* wsCnt = (int*)(wsc + 32 * 1024);                      // 256 B
    int* wsList = (int*)((char*)wsCnt + 256);                  // 256 KB
    float* P = (float*)(wsc + (1 << 20));                      // 16 MB @ +1MB

    hipMemsetAsync(wsCnt, 0, 256, stream);
    score_topk<<<512, 256, 0, stream>>>(x, rw, out, wsW, wsCnt, wsList);
    expert_gemm<<<512, 256, 0, stream>>>(x, neurons, wsCnt, wsList, P);
    combine<<<1024, 256, 0, stream>>>(P, wsW, out);
}